// Round 2
// baseline (2170.823 us; speedup 1.0000x reference)
//
#include <hip/hip_runtime.h>
#include <hip/hip_bf16.h>

typedef float  f32x4  __attribute__((ext_vector_type(4)));
typedef __bf16 bf16x8 __attribute__((ext_vector_type(8)));
typedef unsigned short u16x8 __attribute__((ext_vector_type(8)));

#define NN 16384

__device__ inline bf16x8 cvt_bf16x8(f32x4 a, f32x4 b) {
    bf16x8 r;
    r[0] = (__bf16)a[0]; r[1] = (__bf16)a[1]; r[2] = (__bf16)a[2]; r[3] = (__bf16)a[3];
    r[4] = (__bf16)b[0]; r[5] = (__bf16)b[1]; r[6] = (__bf16)b[2]; r[7] = (__bf16)b[3];
    return r;
}

// ---------------------------------------------------------------------------
// Tt = bf16((H @ W))^T  : H [NN, FIN] f32, W [FIN, FOUT] f32 -> Tt [FOUT, NN] bf16
// ---------------------------------------------------------------------------
template<int FIN, int FOUT>
__global__ __launch_bounds__(256) void xw_t_kernel(
    const float* __restrict__ H, const float* __restrict__ W,
    unsigned short* __restrict__ Tt)
{
    __shared__ float sh[64][FIN + 1];
    const int n0 = blockIdx.x * 64;
    for (int i = threadIdx.x; i < 64 * FIN; i += 256) {
        sh[i / FIN][i % FIN] = H[(size_t)n0 * FIN + i];
    }
    __syncthreads();
    const int nl = threadIdx.x & 63;
    const int f0 = threadIdx.x >> 6;
    for (int f = f0; f < FOUT; f += 4) {
        float s = 0.f;
        #pragma unroll 8
        for (int k = 0; k < FIN; ++k) s += sh[nl][k] * W[k * FOUT + f];
        __bf16 h = (__bf16)s;
        Tt[(size_t)f * NN + n0 + nl] = __builtin_bit_cast(unsigned short, h);
    }
}

// ---------------------------------------------------------------------------
// Layer 1 GC, split-K x4: H = relu(adj @ T + b), adj fp32 in, ALSO writes
// bf16 copy of adj to adjb. grid 1024 blocks x 4 waves; block b owns rows
// [16b,16b+16); wave w owns K-chunk [w*4096,(w+1)*4096). LDS reduce.
// ---------------------------------------------------------------------------
template<int NCB>
__global__ __launch_bounds__(256) void gc1_kernel(
    const float* __restrict__ adj, unsigned short* __restrict__ adjb,
    const unsigned short* __restrict__ Tt,
    const float* __restrict__ bias, float* __restrict__ H)
{
    constexpr int F = NCB * 16;
    constexpr int KC = NN / 4;          // 4096 per wave
    const int lane = threadIdx.x & 63;
    const int wave = threadIdx.x >> 6;  // K-chunk id
    const int rb   = blockIdx.x;        // 0..1023
    const int m    = lane & 15;
    const int kq   = lane >> 4;
    const int k0   = wave * KC;

    const size_t row = (size_t)(rb * 16 + m);
    const float* ap = adj + row * NN + k0 + kq * 8;
    unsigned short* wp = adjb + row * NN + k0 + kq * 8;
    const unsigned short* bp[NCB];
    f32x4 acc[NCB];
    #pragma unroll
    for (int cb = 0; cb < NCB; ++cb) {
        bp[cb] = Tt + (size_t)(cb * 16 + m) * NN + k0 + kq * 8;
        acc[cb] = (f32x4){0.f, 0.f, 0.f, 0.f};
    }

    #pragma unroll 4
    for (int kb = 0; kb < KC / 32; ++kb) {
        const f32x4* a4 = (const f32x4*)(ap + kb * 32);
        f32x4 a0 = a4[0];
        f32x4 a1 = a4[1];
        bf16x8 af = cvt_bf16x8(a0, a1);
        *(u16x8*)(wp + kb * 32) = __builtin_bit_cast(u16x8, af);
        #pragma unroll
        for (int cb = 0; cb < NCB; ++cb) {
            bf16x8 bf = __builtin_bit_cast(bf16x8, *(const u16x8*)(bp[cb] + kb * 32));
            acc[cb] = __builtin_amdgcn_mfma_f32_16x16x32_bf16(af, bf, acc[cb], 0, 0, 0);
        }
    }

    __shared__ float red[4][64][NCB * 4];
    #pragma unroll
    for (int cb = 0; cb < NCB; ++cb)
        #pragma unroll
        for (int i = 0; i < 4; ++i)
            red[wave][lane][cb * 4 + i] = acc[cb][i];
    __syncthreads();
    if (wave == 0) {
        #pragma unroll
        for (int cb = 0; cb < NCB; ++cb) {
            const int c = cb * 16 + m;
            const float bv = bias[c];
            #pragma unroll
            for (int i = 0; i < 4; ++i) {
                const float s = red[0][lane][cb * 4 + i] + red[1][lane][cb * 4 + i]
                              + red[2][lane][cb * 4 + i] + red[3][lane][cb * 4 + i];
                const int r = rb * 16 + kq * 4 + i;
                H[(size_t)r * F + c] = fmaxf(s + bv + bias[c] * 0.f, 0.f);
            }
        }
    }
}

// ---------------------------------------------------------------------------
// Layers 2/3 GC, split-K x4, bf16 adj input.
// ---------------------------------------------------------------------------
template<int NCB>
__global__ __launch_bounds__(256) void gcb_kernel(
    const unsigned short* __restrict__ adjb,
    const unsigned short* __restrict__ Tt,
    const float* __restrict__ bias, float* __restrict__ H)
{
    constexpr int F = NCB * 16;
    constexpr int KC = NN / 4;
    const int lane = threadIdx.x & 63;
    const int wave = threadIdx.x >> 6;
    const int rb   = blockIdx.x;
    const int m    = lane & 15;
    const int kq   = lane >> 4;
    const int k0   = wave * KC;

    const size_t row = (size_t)(rb * 16 + m);
    const unsigned short* ap = adjb + row * NN + k0 + kq * 8;
    const unsigned short* bp[NCB];
    f32x4 acc[NCB];
    #pragma unroll
    for (int cb = 0; cb < NCB; ++cb) {
        bp[cb] = Tt + (size_t)(cb * 16 + m) * NN + k0 + kq * 8;
        acc[cb] = (f32x4){0.f, 0.f, 0.f, 0.f};
    }

    #pragma unroll 4
    for (int kb = 0; kb < KC / 32; ++kb) {
        bf16x8 af = __builtin_bit_cast(bf16x8, *(const u16x8*)(ap + kb * 32));
        #pragma unroll
        for (int cb = 0; cb < NCB; ++cb) {
            bf16x8 bf = __builtin_bit_cast(bf16x8, *(const u16x8*)(bp[cb] + kb * 32));
            acc[cb] = __builtin_amdgcn_mfma_f32_16x16x32_bf16(af, bf, acc[cb], 0, 0, 0);
        }
    }

    __shared__ float red[4][64][NCB * 4];
    #pragma unroll
    for (int cb = 0; cb < NCB; ++cb)
        #pragma unroll
        for (int i = 0; i < 4; ++i)
            red[wave][lane][cb * 4 + i] = acc[cb][i];
    __syncthreads();
    if (wave == 0) {
        #pragma unroll
        for (int cb = 0; cb < NCB; ++cb) {
            const int c = cb * 16 + m;
            const float bv = bias[c];
            #pragma unroll
            for (int i = 0; i < 4; ++i) {
                const float s = red[0][lane][cb * 4 + i] + red[1][lane][cb * 4 + i]
                              + red[2][lane][cb * 4 + i] + red[3][lane][cb * 4 + i];
                const int r = rb * 16 + kq * 4 + i;
                H[(size_t)r * F + c] = fmaxf(s + bv, 0.f);
            }
        }
    }
}

// ---------------------------------------------------------------------------
// Column partial sums of H3 [NN, 64] -> P [64 blocks][64 cols]
// ---------------------------------------------------------------------------
__global__ __launch_bounds__(256) void reduce_cols_kernel(
    const float* __restrict__ H3, float* __restrict__ P)
{
    __shared__ float sm[256];
    const int t = threadIdx.x;
    const int rg = t >> 6;
    const int r0 = blockIdx.x * 256;
    float s = 0.f;
    #pragma unroll 4
    for (int j = 0; j < 64; ++j) {
        const int r = r0 + rg + j * 4;
        s += H3[(size_t)r * 64 + (t & 63)];
    }
    sm[t] = s;
    __syncthreads();
    if (t < 64) P[blockIdx.x * 64 + t] = sm[t] + sm[t + 64] + sm[t + 128] + sm[t + 192];
}

// ---------------------------------------------------------------------------
// Head: y = mean -> relu(y@fcW1+fcb1) -> softmax(z@fcW2+fcb2). 1 block, 64 thr.
// ---------------------------------------------------------------------------
__global__ void head_kernel(
    const float* __restrict__ P,
    const float* __restrict__ fcW1, const float* __restrict__ fcb1,
    const float* __restrict__ fcW2, const float* __restrict__ fcb2,
    float* __restrict__ out)
{
    __shared__ float y[64];
    __shared__ float z1[32];
    __shared__ float lg[2];
    const int t = threadIdx.x;
    float s = 0.f;
    for (int w = 0; w < 64; ++w) s += P[w * 64 + t];
    y[t] = s * (1.0f / 16384.0f);
    __syncthreads();
    if (t < 32) {
        float a = fcb1[t];
        for (int k = 0; k < 64; ++k) a += y[k] * fcW1[k * 32 + t];
        z1[t] = fmaxf(a, 0.f);
    }
    __syncthreads();
    if (t < 2) {
        float a = fcb2[t];
        for (int j = 0; j < 32; ++j) a += z1[j] * fcW2[j * 2 + t];
        lg[t] = a;
    }
    __syncthreads();
    if (t == 0) {
        const float mx = fmaxf(lg[0], lg[1]);
        const float e0 = expf(lg[0] - mx), e1 = expf(lg[1] - mx);
        out[0] = e0 / (e0 + e1);
        out[1] = e1 / (e0 + e1);
    }
}

extern "C" void kernel_launch(void* const* d_in, const int* in_sizes, int n_in,
                              void* d_out, int out_size, void* d_ws, size_t ws_size,
                              hipStream_t stream) {
    const float* x     = (const float*)d_in[0];
    const float* adj   = (const float*)d_in[1];
    const float* W1    = (const float*)d_in[3];
    const float* b1    = (const float*)d_in[4];
    const float* W2    = (const float*)d_in[5];
    const float* b2    = (const float*)d_in[6];
    const float* W3    = (const float*)d_in[7];
    const float* b3    = (const float*)d_in[8];
    const float* fcW1  = (const float*)d_in[9];
    const float* fcb1  = (const float*)d_in[10];
    const float* fcW2  = (const float*)d_in[11];
    const float* fcb2  = (const float*)d_in[12];
    float* out = (float*)d_out;

    char* ws = (char*)d_ws;
    unsigned short* adjb = (unsigned short*)(ws + 0);            // NN*NN bf16 = 512 MiB
    size_t off = (size_t)NN * NN * sizeof(unsigned short);
    unsigned short* Tt = (unsigned short*)(ws + off);            // 2 MiB max
    float* H1 = (float*)(ws + off + (2u << 20));                 // 2 MiB
    float* H2 = (float*)(ws + off + (6u << 20));                 // 3 MiB
    float* H3 = (float*)(ws + off + (10u << 20));                // 4 MiB
    float* P  = (float*)(ws + off + (15u << 20));                // 16 KiB

    xw_t_kernel<128, 32><<<NN / 64, 256, 0, stream>>>(x, W1, Tt);
    gc1_kernel<2><<<NN / 16, 256, 0, stream>>>(adj, adjb, Tt, b1, H1);
    xw_t_kernel<32, 48><<<NN / 64, 256, 0, stream>>>(H1, W2, Tt);
    gcb_kernel<3><<<NN / 16, 256, 0, stream>>>(adjb, Tt, b2, H2);
    xw_t_kernel<48, 64><<<NN / 64, 256, 0, stream>>>(H2, W3, Tt);
    gcb_kernel<4><<<NN / 16, 256, 0, stream>>>(adjb, Tt, b3, H3);
    reduce_cols_kernel<<<64, 256, 0, stream>>>(H3, P);
    head_kernel<<<1, 64, 0, stream>>>(P, fcW1, fcb1, fcW2, fcb2, out);
}